// Round 19
// baseline (800.562 us; speedup 1.0000x reference)
//
#include <hip/hip_runtime.h>

// PWC-Net cost volume, fp32. B=4, C=128, H=256, W=448, 81 shifts.
// out[b, di*9+dj, h, w] = (1/128) * sum_c feat1[b,c,h,w] * feat2[b,c,h+di-4,w+dj-4]
//
// Block = (b,h), 512 thr / 8 waves. Thread owns (di, 8px): it = tid ->
// di = it/56, m = it%56 (504 active). acc[9][8] = 72 (AGPR-able; R8 ran
// this acc size spill-free at cap 128).
//
// Per channel one LDS buffer: 10 rows x 114 slots(16B). Rows 0..8 = feat2
// h-4..h+4 (OOB rows staged as zeros from zws), row 9 = feat1 row h.
// INTERLEAVED slot permutation (R6): atom 2x -> slot x, atom 2x+1 -> slot
// 57+x (atom a covers cols 4a-4..4a-1). Slot 0 = atom 0 (cols -4..-1) and
// slot 113 = atom 113 (cols 448..451) are zero halo: zeroed once, never
// staged -> edge semantics free. Window for 8px at m = atoms 2m..2m+3 ->
// slots m, 57+m, m+1, 58+m; f1 atoms 2m+1,2m+2 -> row-9 slots 57+m, m+1.
// All six ds_read_b128 are lane-stride-16B -> 2-way bank alias = free.
// DS/body = 48 reads + 20 stage writes (~816 cy) vs R16's 1008 (-19%),
// at 2x the per-thread FMA (better DS/VALU overlap).
//
// Stage = 20 issues (10 rows x {even-atoms, odd-atoms}): issue j (r=j>>1,
// hf=j&1): lanes 0..55 load 16B from src col (hf ? 8*lane : 8*lane+4)
// -> dest slot (hf ? 57+lane : 1+lane) [linear lane*16 dest, permutation
// pre-applied on the global source]. Wave wid takes j = wid+8k, k<nIss,
// nIss = wid<4 ? 3 : 2.
//
// Ring-3, drain-old counted vmcnt (R16's proven schedule): body t waits
// vmcnt(nIss) (drains stage(t), issued 2 bodies ago; stage(t+1) stays in
// flight), barrier, stages ch t+2 -> buf (t+2)%3, computes buf t%3.

typedef __attribute__((ext_vector_type(4))) float f32x4;

#define GLAS(p) ((const __attribute__((address_space(1))) unsigned int*)(p))
#define LDAS(p) ((__attribute__((address_space(3))) unsigned int*)(p))

__global__ __launch_bounds__(512, 4) void cv_kernel(
    const float* __restrict__ feat1,
    const float* __restrict__ feat2,
    const float* __restrict__ zws,
    float* __restrict__ out)
{
    constexpr int C = 128, H = 256, W = 448;
    constexpr size_t HW = (size_t)H * W;
    constexpr int ROWB = 114 * 16;     // 1824 B
    constexpr int BUFB = 10 * ROWB;    // 18240 B
    __shared__ __align__(16) char f2s[3 * BUFB];   // 54720 B

    const int tid  = threadIdx.x;
    const int wid  = tid >> 6;
    const int lane = tid & 63;

    // XCD-contiguous (b,h) mapping (1024 = 8*128, bijective)
    const int lin = (blockIdx.x & 7) * 128 + (blockIdx.x >> 3);
    const int b = lin >> 8, h = lin & 255;

    const int it = (tid < 504) ? tid : 503;
    const int di = it / 56;
    const int m  = it - di * 56;       // 0..55

    // Zero LDS once (halo slots 0/113 persist; staged slots overwritten).
    for (int i = tid; i < (int)sizeof(f2s) / 16; i += 512)
        *(f32x4*)(f2s + i * 16) = (f32x4){0.f, 0.f, 0.f, 0.f};

    // Staging descriptors. Issue j = wid + 8k: row r=j>>1 (0..9), hf=j&1.
    // hf=0: slots 1..56  <- even atoms 2..112,  src col 8*lane+4.
    // hf=1: slots 57..112 <- odd atoms 1..111,  src col 8*lane.
    // r==9 -> feat1 row h; else feat2 row h+r-4 (OOB -> zws, step 0).
    const int nIss = (wid < 4) ? 3 : 2;
    const float* sp[3]; unsigned sstep[3]; int sdst[3];
#pragma unroll
    for (int k = 0; k < 3; ++k) {
        if (k < nIss) {
            const int j  = wid + 8 * k;
            const int r  = j >> 1, hf = j & 1;
            const int colf = (lane < 56) ? (hf ? 8 * lane : 8 * lane + 4) : 0;
            if (r == 9) {
                sp[k] = feat1 + ((size_t)b * C * H + (size_t)h) * W + colf;
                sstep[k] = (unsigned)HW;
            } else {
                const int hr = h + r - 4;
                const bool ok = (hr >= 0) && (hr < H);
                sp[k] = ok ? (feat2 + ((size_t)b * C * H + (size_t)hr) * W + colf) : zws;
                sstep[k] = ok ? (unsigned)HW : 0u;
            }
            sdst[k] = r * ROWB + (hf ? 57 * 16 : 16);
        }
    }

    // Read offsets (bytes). f2 row di: atoms 2m..2m+3 -> slots m,57+m,m+1,58+m.
    const int oL  = di * ROWB + m * 16;
    const int oC1 = di * ROWB + (57 + m) * 16;
    const int oC2 = di * ROWB + (m + 1) * 16;
    const int oR  = di * ROWB + (58 + m) * 16;
    // f1 row 9: atoms 2m+1, 2m+2.
    const int oA0 = 9 * ROWB + (57 + m) * 16;
    const int oA1 = 9 * ROWB + (m + 1) * 16;

    float acc[9][8];
#pragma unroll
    for (int j = 0; j < 9; ++j)
#pragma unroll
        for (int p = 0; p < 8; ++p) acc[j][p] = 0.0f;

    __syncthreads();   // LDS zeros visible before first stage lands

#define STAGE(BUFOFS) do { \
    _Pragma("unroll") \
    for (int k = 0; k < 3; ++k) { \
        if (k < nIss) { \
            if (lane < 56) \
                __builtin_amdgcn_global_load_lds(GLAS(sp[k]), \
                    LDAS(f2s + (BUFOFS) + sdst[k]), 16, 0, 0); \
            sp[k] += sstep[k]; \
        } \
    } } while (0)

#define COMP(BUFOFS) do { \
    const char* lb = f2s + (BUFOFS); \
    const f32x4 L  = *(const f32x4*)(lb + oL); \
    const f32x4 C1 = *(const f32x4*)(lb + oC1); \
    const f32x4 C2 = *(const f32x4*)(lb + oC2); \
    const f32x4 R  = *(const f32x4*)(lb + oR); \
    const f32x4 A0 = *(const f32x4*)(lb + oA0); \
    const f32x4 A1 = *(const f32x4*)(lb + oA1); \
    const float w[16] = {L.x, L.y, L.z, L.w, C1.x, C1.y, C1.z, C1.w, \
                         C2.x, C2.y, C2.z, C2.w, R.x, R.y, R.z, R.w}; \
    const float a[8]  = {A0.x, A0.y, A0.z, A0.w, A1.x, A1.y, A1.z, A1.w}; \
    _Pragma("unroll") \
    for (int dj = 0; dj < 9; ++dj) { \
        _Pragma("unroll") \
        for (int p = 0; p < 8; ++p) \
            acc[dj][p] = fmaf(a[p], w[dj + p], acc[dj][p]); \
    } } while (0)

// MODE 0: wait n + stage | 1: wait n, no stage | 2: wait 0, no stage
#define BODY(BUF, NBUF, MODE) do { \
    if ((MODE) <= 1) { \
        if (wid < 4) asm volatile("s_waitcnt vmcnt(3)" ::: "memory"); \
        else         asm volatile("s_waitcnt vmcnt(2)" ::: "memory"); \
    } else { \
        asm volatile("s_waitcnt vmcnt(0)" ::: "memory"); \
    } \
    __builtin_amdgcn_s_barrier(); \
    __builtin_amdgcn_sched_barrier(0); \
    if ((MODE) == 0) STAGE((NBUF) * BUFB); \
    __builtin_amdgcn_sched_barrier(0); \
    COMP((BUF) * BUFB); \
  } while (0)

    // Prologue: stage ch0 -> buf0.
    STAGE(0 * BUFB);

    // Body 0 (special): drain prologue; stage ch1->buf1, ch2->buf2; comp ch0.
    {
        asm volatile("s_waitcnt vmcnt(0)" ::: "memory");
        __builtin_amdgcn_s_barrier();
        __builtin_amdgcn_sched_barrier(0);
        STAGE(1 * BUFB);
        STAGE(2 * BUFB);
        __builtin_amdgcn_sched_barrier(0);
        COMP(0 * BUFB);
    }

    // Bodies 1..123 (41 x 3), then 124,125, tail 126 (wait n), 127 (wait 0).
#pragma unroll 1
    for (int g = 0; g < 41; ++g) {
        BODY(1, 0, 0);
        BODY(2, 1, 0);
        BODY(0, 2, 0);
    }
    BODY(1, 0, 0);   // t=124, stages ch126 -> buf0
    BODY(2, 1, 0);   // t=125, stages ch127 -> buf1
    BODY(0, 2, 1);   // t=126
    BODY(1, 0, 2);   // t=127

#undef STAGE
#undef COMP
#undef BODY

    if (tid < 504) {
        const float s = 1.0f / 128.0f;
        float* ob = out + (((size_t)(b * 81 + di * 9)) * H + h) * W + m * 8;
#pragma unroll
        for (int dj = 0; dj < 9; ++dj) {
            f32x4 o0 = {acc[dj][0] * s, acc[dj][1] * s,
                        acc[dj][2] * s, acc[dj][3] * s};
            f32x4 o1 = {acc[dj][4] * s, acc[dj][5] * s,
                        acc[dj][6] * s, acc[dj][7] * s};
            float* op = ob + (size_t)dj * HW;
            *(f32x4*)(op)     = o0;
            *(f32x4*)(op + 4) = o1;
        }
    }
}

extern "C" void kernel_launch(void* const* d_in, const int* in_sizes, int n_in,
                              void* d_out, int out_size, void* d_ws, size_t ws_size,
                              hipStream_t stream) {
    const float* feat1 = (const float*)d_in[0];
    const float* feat2 = (const float*)d_in[1];
    float* out = (float*)d_out;
    // 256 zeroed bytes: broadcast-source for vertically-OOB feat2 rows.
    hipMemsetAsync(d_ws, 0, 256, stream);
    cv_kernel<<<dim3(1024), dim3(512), 0, stream>>>(
        feat1, feat2, (const float*)d_ws, out);
}

// Round 20
// 303.314 us; speedup vs baseline: 2.6394x; 2.6394x over previous
//
#include <hip/hip_runtime.h>

// PWC-Net cost volume, fp32. B=4, C=128, H=256, W=448, 81 shifts.
// out[b, di*9+dj, h, w] = (1/128) * sum_c feat1[b,c,h,w] * feat2[b,c,h+di-4,w+dj-4]
//
// WAVE-PRIVATE LDS, ZERO BARRIERS. One 64-thread block per (b,h,di): 9216
// waves. Lane owns 8 px (m = lane, 56 active). Per channel the wave stages
// ONLY its own feat2 row h+di-4 into a private ring-3 LDS slice via
// global_load_lds; synchronization is purely the wave's own counted vmcnt —
// no s_barrier, no cross-wave visibility needed (R8's independence + R16's
// LDS-window economy). f1 (cols 8m..8m+7, own data) rides in registers,
// ping-pong, distance-1 (L1-warm: 9 di-waves share it).
//
// LDS buffer/channel = 114 slots x 16B, interleaved permutation tau(2x)=x,
// tau(2x+1)=57+x (atom a = cols 4a-4..4a-1). Slots 0/113 (atoms 0/113) are
// zero halo: written once, never staged -> edges free, no store masking.
// Window atoms 2m..2m+3 -> slots m, 57+m, m+1, 58+m: all lane-stride-16B
// ds_read_b128 = 2-way bank alias = free. Stage = 2 issues/channel:
//   A: lanes 1..56, slot l <- src col 8l-4 (even atoms 2..112)
//   B: lanes 0..55, slot 57+l <- src col 8l (odd atoms 1..111)
// (linear LDS dest = base + lane*16; tau pre-applied on global source).
// OOB rows stage zeros from zws (ring reuse needs explicit zeros).
//
// Per body t: wait vmcnt(2) [drains f1(t) (issued t-1) + stage(t) (issued
// t-2, ~2-body cover); leaves stage(t+1)]; issue f1(t+1) then stage(t+2);
// 4 ds_read + 72 FMA. acc[9][8]=72 regs; demand ~126; launch_bounds(64,3)
// -> cap 170 (acc72 NEEDS cap>=170: R18's spill was cap 128).

typedef __attribute__((ext_vector_type(4))) float f32x4;

#define GLAS(p) ((const __attribute__((address_space(1))) unsigned int*)(p))
#define LDAS(p) ((__attribute__((address_space(3))) unsigned int*)(p))

__global__ __launch_bounds__(64, 3) void cv_kernel(
    const float* __restrict__ feat1,
    const float* __restrict__ feat2,
    const float* __restrict__ zws,
    float* __restrict__ out)
{
    constexpr int C = 128, H = 256, W = 448;
    constexpr size_t HW = (size_t)H * W;
    constexpr int BUFB = 114 * 16;               // 1824 B per channel buffer
    __shared__ __align__(16) char lds[3 * BUFB]; // 5472 B per block (1 wave)

    const int lane = threadIdx.x;                // 0..63
    const int m    = (lane < 56) ? lane : 55;

    // XCD-contiguous mapping (9216 = 8*1152, bijective): the 9 di-waves of a
    // given (b,h) are consecutive -> same XCD -> f1/f2 rows L2-shared.
    const int item = (blockIdx.x & 7) * 1152 + (blockIdx.x >> 3);
    const int di = item % 9;
    const int bh = item / 9;
    const int h  = bh & 255, b = bh >> 8;
    const int hr = h + di - 4;
    const bool rowok = (hr >= 0) && (hr < H);

    // Zero the halo slots (0 and 113 of each ring buffer) once.
    if (lane < 3) {
        *(f32x4*)(lds + lane * BUFB)            = (f32x4){0.f, 0.f, 0.f, 0.f};
        *(f32x4*)(lds + lane * BUFB + 113 * 16) = (f32x4){0.f, 0.f, 0.f, 0.f};
    }
    asm volatile("s_waitcnt lgkmcnt(0)" ::: "memory");

    // Staging sources (tau pre-applied). OOB row -> zws (zeros), step 0.
    const float* f2base = feat2 + ((size_t)b * C * H + (size_t)(rowok ? hr : 0)) * W;
    const float* spA; const float* spB; unsigned sstep;
    if (rowok) {
        spA = f2base + (8 * lane - 4);   // used by lanes 1..56 only
        spB = f2base + (8 * lane);       // used by lanes 0..55 only
        sstep = (unsigned)HW;
    } else {
        spA = zws + lane * 4;
        spB = zws + lane * 4;
        sstep = 0u;
    }
    const bool mA = (lane >= 1) && (lane <= 56);
    const bool mB = (lane <= 55);

    // f1: own 8 cols, register ping-pong.
    unsigned f1o = (unsigned)(((b * C * H) + h) * W + 8 * m);

    // Window read offsets within a buffer (bytes).
    const int oL  = m * 16;
    const int oC1 = (57 + m) * 16;
    const int oC2 = (m + 1) * 16;
    const int oR  = (58 + m) * 16;

    float acc[9][8];
#pragma unroll
    for (int j = 0; j < 9; ++j)
#pragma unroll
        for (int p = 0; p < 8; ++p) acc[j][p] = 0.0f;

#define STAGE(NS) do { \
    if (mA) __builtin_amdgcn_global_load_lds(GLAS(spA), LDAS(lds + (NS) * BUFB), 16, 0, 0); \
    if (mB) __builtin_amdgcn_global_load_lds(GLAS(spB), LDAS(lds + (NS) * BUFB + 912), 16, 0, 0); \
    spA += sstep; spB += sstep; } while (0)

#define COMP(BUF) do { \
    const char* lb = lds + (BUF) * BUFB; \
    const f32x4 L  = *(const f32x4*)(lb + oL); \
    const f32x4 C1 = *(const f32x4*)(lb + oC1); \
    const f32x4 C2 = *(const f32x4*)(lb + oC2); \
    const f32x4 R  = *(const f32x4*)(lb + oR); \
    const float w[16] = {L.x, L.y, L.z, L.w, C1.x, C1.y, C1.z, C1.w, \
                         C2.x, C2.y, C2.z, C2.w, R.x, R.y, R.z, R.w}; \
    const float a[8]  = {f1c0.x, f1c0.y, f1c0.z, f1c0.w, \
                         f1c1.x, f1c1.y, f1c1.z, f1c1.w}; \
    _Pragma("unroll") \
    for (int dj = 0; dj < 9; ++dj) { \
        _Pragma("unroll") \
        for (int p = 0; p < 8; ++p) \
            acc[dj][p] = fmaf(a[p], w[dj + p], acc[dj][p]); \
    } } while (0)

// MODE 0: steady | 1: no stage (t=126) | 2: tail (t=127)
#define BODY(BUF, NS, MODE) do { \
    if ((MODE) <= 1) asm volatile("s_waitcnt vmcnt(2)" ::: "memory"); \
    else             asm volatile("s_waitcnt vmcnt(0)" ::: "memory"); \
    __builtin_amdgcn_sched_barrier(0); \
    f32x4 f1n0, f1n1; \
    if ((MODE) <= 1) { \
        f1n0 = *(const f32x4*)(feat1 + f1o); \
        f1n1 = *(const f32x4*)(feat1 + f1o + 4); \
        f1o += (unsigned)HW; \
    } \
    if ((MODE) == 0) STAGE(NS); \
    __builtin_amdgcn_sched_barrier(0); \
    COMP(BUF); \
    if ((MODE) <= 1) { f1c0 = f1n0; f1c1 = f1n1; } \
  } while (0)

    // Prologue: stage ch0 -> buf0; f1(0); stage ch1 -> buf1.
    STAGE(0);
    f32x4 f1c0 = *(const f32x4*)(feat1 + f1o);
    f32x4 f1c1 = *(const f32x4*)(feat1 + f1o + 4);
    f1o += (unsigned)HW;
    STAGE(1);

    // Bodies 0..125 (42 x 3), tail 126 (no stage), 127 (drain).
#pragma unroll 1
    for (int g = 0; g < 42; ++g) {
        BODY(0, 2, 0);
        BODY(1, 0, 0);
        BODY(2, 1, 0);
    }
    BODY(0, 2, 1);   // t = 126: f1(127) only
    BODY(1, 0, 2);   // t = 127

#undef STAGE
#undef COMP
#undef BODY

    if (lane < 56) {
        const float s = 1.0f / 128.0f;
        float* ob = out + (((size_t)(b * 81 + di * 9)) * H + h) * W + 8 * m;
#pragma unroll
        for (int dj = 0; dj < 9; ++dj) {
            f32x4 o0 = {acc[dj][0] * s, acc[dj][1] * s,
                        acc[dj][2] * s, acc[dj][3] * s};
            f32x4 o1 = {acc[dj][4] * s, acc[dj][5] * s,
                        acc[dj][6] * s, acc[dj][7] * s};
            float* op = ob + (size_t)dj * HW;
            *(f32x4*)(op)     = o0;
            *(f32x4*)(op + 4) = o1;
        }
    }
}

extern "C" void kernel_launch(void* const* d_in, const int* in_sizes, int n_in,
                              void* d_out, int out_size, void* d_ws, size_t ws_size,
                              hipStream_t stream) {
    const float* feat1 = (const float*)d_in[0];
    const float* feat2 = (const float*)d_in[1];
    float* out = (float*)d_out;
    // 1 KiB zeros: stage source for vertically-OOB feat2 rows (lane*4 floats).
    hipMemsetAsync(d_ws, 0, 1024, stream);
    cv_kernel<<<dim3(9216), dim3(64), 0, stream>>>(
        feat1, feat2, (const float*)d_ws, out);
}